// Round 6
// baseline (214.614 us; speedup 1.0000x reference)
//
#include <hip/hip_runtime.h>
#include <stdint.h>

// Bloom filter, 2^27 bits, 7 hashes = 7 CONSECUTIVE bits starting at
//   p = ((uint32)v * 2654435761u) & (2^27 - 1)   (wraps mod 2^27)
// Harness dtypes: integer inputs -> int32; bool output -> int32 (0/1).
//
// R14: pair-AND filter H2 replaces nibble filter H.
//   R12/R13 post-mortem: ILP-widening the query (16/thread) loses to R11's
//   8/thread + more waves (WAR-serialized sub-batches; NT partial-line
//   double-flush -> WRITE 53MB). Query reverted to R11 structure.
//   New lever: the 7-bit window always fully contains THREE consecutive
//   pair-bits (q0=((p+1)&mask)>>1), so an 8MB pair-AND table H2 passes only
//   ~7% of queries vs the nibble filter's ~13% -> halves the random fine
//   gathers (the dominant query cost, most of the 187MB FETCH).
//   H2 aliases the lists region (dead after build_bitmap) -> no ws growth.
//   Insert bundle: R12 config (best measured: CHUNK 8192/512th scatter,
//   full-region 512th build); build writes bits only; tiny build_h2 pass.

#define NUM_BITS_LOG2 27
#define NUM_BITS (1u << NUM_BITS_LOG2)
#define BIT_MASK (NUM_BITS - 1u)
#define NUM_WORDS (NUM_BITS >> 6)             // 2^21 u64 words = 16 MiB
#define WORD_MASK (NUM_WORDS - 1u)
#define PRIME 2654435761u

#define H2_WORDS (1u << 20)                   // 2^26 pair-bits = 2^20 u64 = 8 MiB
#define H2_WMASK (H2_WORDS - 1u)

#define NBUCKETS 512
#define BKT_SHIFT (NUM_BITS_LOG2 - 9)         // 18: region = 2^18 bits
#define REGION_WORDS (1u << (BKT_SHIFT - 6))  // 4096 u64 = 32 KiB
#define CAP 8688u                             // per-bucket list capacity (mean 7813 + 9.9 sigma)
#define CHUNK 8192u                           // values per sorted chunk (32 KiB LDS)

typedef int vint4 __attribute__((ext_vector_type(4)));
typedef unsigned long long vull2 __attribute__((ext_vector_type(2)));

// ---------------- workspace layout (bytes) ----------------
// [0, 16777216)            bits   u64 x 2^21   (16 MiB)
// [16777216, 34570240)     lists  u32 x 512*8688   (17,793,024)
// [34570240, 34572288)     gcnt   u32 x 512
// H2 (u64 x 2^20, 8 MiB) ALIASES [16777216, 25165824) -- lists are dead
// after build_bitmap consumes them; build_h2 runs strictly after.
#define WS_H2_ONLY 25165824ull
#define WS_FULL    34572288ull

// ---------- tiny init: zero the global bucket cursors ----------
__global__ __launch_bounds__(512) void init_gcnt_kernel(uint32_t* __restrict__ gcnt) {
    gcnt[threadIdx.x] = 0u;
}

// ---------- phase A: per-chunk LDS counting sort -> coalesced list flush ----------
// 512 threads/block, 1 bin/thread, wave-shuffle scan (3 syncs), 16 vals/thread.
__global__ __launch_bounds__(512) void scatter_kernel(
    const int* __restrict__ vals, int n,
    uint32_t* __restrict__ lists, uint32_t* __restrict__ gcnt)
{
    __shared__ uint32_t hist[NBUCKETS];
    __shared__ uint32_t cur[NBUCKETS];     // local slot cursors
    __shared__ uint32_t gdelta[NBUCKETS];  // slot i -> global list index (u32 wrap ok)
    __shared__ uint32_t wsum[8];
    __shared__ uint32_t wexc[8];
    __shared__ uint32_t total_s;
    __shared__ uint32_t sortbuf[CHUNK];
    const uint32_t tid = threadIdx.x;
    const uint32_t lane = tid & 63u;
    const uint32_t wv = tid >> 6;
    const uint32_t un = (uint32_t)n;
    const uint32_t nchunks = (un + CHUNK - 1u) / CHUNK;

    for (uint32_t c = blockIdx.x; c < nchunks; c += gridDim.x) {
        const uint32_t base = c * CHUNK;
        const bool full = (base + CHUNK <= un);

        hist[tid] = 0u;
        __syncthreads();

        // ---- pass 1: histogram (+ direct write of rare straddle dups) ----
        vint4 vv[4];                                    // 16 values/thread
        if (full) {
            const vint4* src = (const vint4*)(vals + base);
            #pragma unroll
            for (int k = 0; k < 4; ++k) vv[k] = src[(uint32_t)k * 512u + tid];
            #pragma unroll
            for (int k = 0; k < 4; ++k) {
                #pragma unroll
                for (int j = 0; j < 4; ++j) {
                    uint32_t p = ((uint32_t)vv[k][j] * PRIME) & BIT_MASK;
                    uint32_t b1 = p >> BKT_SHIFT;
                    atomicAdd(&hist[b1], 1u);
                    uint32_t b2 = ((p + 6u) & BIT_MASK) >> BKT_SHIFT;
                    if (b2 != b1) {                     // ~92 total in whole input
                        uint32_t s2 = atomicAdd(&gcnt[b2], 1u);
                        if (s2 < CAP) lists[b2 * CAP + s2] = p;
                    }
                }
            }
        } else {
            #pragma unroll
            for (int k = 0; k < 16; ++k) {
                uint32_t idx = base + (uint32_t)k * 512u + tid;
                if (idx < un) {
                    uint32_t p = ((uint32_t)vals[idx] * PRIME) & BIT_MASK;
                    uint32_t b1 = p >> BKT_SHIFT;
                    atomicAdd(&hist[b1], 1u);
                    uint32_t b2 = ((p + 6u) & BIT_MASK) >> BKT_SHIFT;
                    if (b2 != b1) {
                        uint32_t s2 = atomicAdd(&gcnt[b2], 1u);
                        if (s2 < CAP) lists[b2 * CAP + s2] = p;
                    }
                }
            }
        }
        __syncthreads();

        // ---- wave-shuffle inclusive scan over 512 bins ----
        const uint32_t c0 = hist[tid];
        uint32_t x = c0;
        #pragma unroll
        for (uint32_t d = 1; d < 64; d <<= 1) {
            uint32_t y = __shfl_up(x, d, 64);
            if (lane >= d) x += y;
        }
        if (lane == 63u) wsum[wv] = x;
        __syncthreads();
        if (wv == 0) {
            uint32_t t8 = (lane < 8u) ? wsum[lane] : 0u;
            #pragma unroll
            for (uint32_t d = 1; d < 8; d <<= 1) {
                uint32_t y = __shfl_up(t8, d, 64);
                if (lane >= d) t8 += y;
            }
            if (lane < 8u) wexc[lane] = t8 - wsum[lane];   // exclusive wave offset
        }
        __syncthreads();
        const uint32_t inc = x + wexc[wv];                 // inclusive scan of bin tid
        const uint32_t lb = inc - c0;                      // exclusive (local base)
        if (tid == NBUCKETS - 1) total_s = inc;

        // ---- reserve global chunk; slot->global mapping ----
        uint32_t go = c0 ? atomicAdd(&gcnt[tid], c0) : 0u;
        cur[tid] = lb;
        gdelta[tid] = tid * CAP + go - lb;                 // u32 wraparound exact
        __syncthreads();

        // ---- pass 2: counting-sort p values into LDS ----
        if (full) {
            #pragma unroll
            for (int k = 0; k < 4; ++k) {
                #pragma unroll
                for (int j = 0; j < 4; ++j) {
                    uint32_t p = ((uint32_t)vv[k][j] * PRIME) & BIT_MASK;
                    uint32_t b1 = p >> BKT_SHIFT;
                    uint32_t s = atomicAdd(&cur[b1], 1u);
                    sortbuf[s] = p;
                }
            }
        } else {
            #pragma unroll
            for (int k = 0; k < 16; ++k) {
                uint32_t idx = base + (uint32_t)k * 512u + tid;
                if (idx < un) {
                    uint32_t p = ((uint32_t)vals[idx] * PRIME) & BIT_MASK;
                    uint32_t b1 = p >> BKT_SHIFT;
                    uint32_t s = atomicAdd(&cur[b1], 1u);
                    sortbuf[s] = p;
                }
            }
        }
        __syncthreads();

        // ---- flush: slots grouped by ascending bucket -> coalesced run writes ----
        const uint32_t total = total_s;
        for (uint32_t i = tid; i < total; i += 512u) {
            uint32_t p = sortbuf[i];
            uint32_t b = p >> BKT_SHIFT;
            uint32_t dst = gdelta[b] + i;
            if (dst - b * CAP < CAP) lists[dst] = p;    // clamp: statistically unreachable
        }
        __syncthreads();                                // protect LDS reuse next iter
    }
}

// ---------- phase B: build region bitmap in LDS, emit bits ----------
__device__ __forceinline__ void set_window(unsigned long long* bm, uint32_t p, uint32_t b) {
    int d = (int)((p - (b << BKT_SHIFT)) & BIT_MASK);
    if (d >= (1 << 26)) d -= (1 << 27);                 // dup from prev region / wrap
    if (d < -6 || d >= (1 << BKT_SHIFT)) return;        // safety guard
    if (d < 0) {
        atomicOr(&bm[0], 0x7Full >> (uint32_t)(-d));
    } else {
        uint32_t w = (uint32_t)d >> 6, s = (uint32_t)d & 63u;
        atomicOr(&bm[w], 0x7Full << s);
        if (s > 57u) atomicOr(&bm[w + 1], 0x7Full >> (64u - s));  // slack word absorbs
    }
}

__global__ __launch_bounds__(512) void build_bitmap_kernel(
    const uint32_t* __restrict__ lists, const uint32_t* __restrict__ gcnt,
    unsigned long long* __restrict__ bits)
{
    __shared__ unsigned long long bm[REGION_WORDS + 1];
    const uint32_t b = blockIdx.x, tid = threadIdx.x;
    for (uint32_t i = tid; i < REGION_WORDS + 1; i += 512) bm[i] = 0ull;
    __syncthreads();

    // dense bucket list -> fully coalesced cooperative read
    const uint32_t m = min(gcnt[b], CAP);
    const uint32_t base = b * CAP;
    for (uint32_t i = tid; i < m; i += 512) set_window(bm, lists[base + i], b);
    __syncthreads();

    const uint32_t out_base = b * REGION_WORDS;
    for (uint32_t i = tid; i < REGION_WORDS / 2; i += 512) {
        vull2 w; w[0] = bm[i * 2]; w[1] = bm[i * 2 + 1];
        *((vull2*)(bits + out_base) + i) = w;           // temporal: warm L3 for query
    }
}

// ---------- H2 build: pair-AND of bits, compacted ----------
// out bit k of compact32 = bits[2k] & bits[2k+1] of input word
__device__ __forceinline__ unsigned long long compact32(unsigned long long a) {
    unsigned long long t = a & (a >> 1);
    unsigned long long x = t & 0x5555555555555555ull;
    x = (x | (x >> 1))  & 0x3333333333333333ull;
    x = (x | (x >> 2))  & 0x0F0F0F0F0F0F0F0Full;
    x = (x | (x >> 4))  & 0x00FF00FF00FF00FFull;
    x = (x | (x >> 8))  & 0x0000FFFF0000FFFFull;
    x = (x | (x >> 16)) & 0x00000000FFFFFFFFull;
    return x;
}

// H2 word i covers pairs 64i..64i+63 = bits words 2i, 2i+1. Grid exact: 2^20/256.
__global__ __launch_bounds__(256) void build_h2_kernel(
    const unsigned long long* __restrict__ bits, unsigned long long* __restrict__ H2)
{
    uint32_t i = blockIdx.x * 256 + threadIdx.x;
    vull2 a = *((const vull2*)bits + i);                // hot in L2/L3 from build
    H2[i] = compact32(a[0]) | (compact32(a[1]) << 32);
}

// ---------- query: H2 pair-filter, fine bitmap only on pass ----------
__device__ __forceinline__ int query_one_branchy(uint32_t v,
                                                 const unsigned long long* __restrict__ bits) {
    uint32_t p = (v * PRIME) & BIT_MASK;
    uint32_t w = p >> 6, s = p & 63u;
    unsigned long long lo = bits[w];
    unsigned long long win;
    if (s <= 57u) win = lo >> s;
    else win = (lo >> s) | (bits[(w + 1u) & WORD_MASK] << (64u - s));
    return ((win & 0x7Full) == 0x7Full) ? 1 : 0;
}

// 8 queries/thread (R11 structure): 8 H2 probes in flight, then masked gathers.
// Window [p,p+6] always fully contains pairs q0,q0+1,q0+2 with q0=((p+1)&M)>>1;
// any of those pairs not all-set => definite miss. Pass rate ~7%.
__global__ __launch_bounds__(256) void query_kernelH2(
    const int* __restrict__ vals, int n,
    const unsigned long long* __restrict__ bits,
    const unsigned long long* __restrict__ H2, int* __restrict__ out)
{
    int t = blockIdx.x * 256 + threadIdx.x;
    int base = t * 8;
    if (base + 7 < n) {
        vint4 v0 = __builtin_nontemporal_load((const vint4*)(vals + base));
        vint4 v1 = __builtin_nontemporal_load((const vint4*)(vals + base + 4));
        uint32_t p[8], q0[8], sh[8];
        #pragma unroll
        for (int j = 0; j < 4; ++j) {
            p[j]     = ((uint32_t)v0[j] * PRIME) & BIT_MASK;
            p[j + 4] = ((uint32_t)v1[j] * PRIME) & BIT_MASK;
        }
        unsigned long long hh[8];
        #pragma unroll
        for (int j = 0; j < 8; ++j) {           // 8 independent H2 probes (mostly L2)
            q0[j] = ((p[j] + 1u) & BIT_MASK) >> 1;
            sh[j] = q0[j] & 63u;
            hh[j] = H2[q0[j] >> 6];
        }
        uint32_t pass[8];
        #pragma unroll
        for (int j = 0; j < 8; ++j) {           // straddle (sh>61): ~3.1% lanes
            uint32_t trip = (uint32_t)(hh[j] >> sh[j]);
            if (sh[j] > 61u)
                trip |= (uint32_t)(H2[((q0[j] >> 6) + 1u) & H2_WMASK] << (64u - sh[j]));
            pass[j] = ((trip & 7u) == 7u);
        }
        unsigned long long lo[8], hi[8];
        uint32_t w[8], s[8];
        #pragma unroll
        for (int j = 0; j < 8; ++j) {           // masked fine gathers (~7% lanes), CACHED
            w[j] = p[j] >> 6; s[j] = p[j] & 63u;
            lo[j] = 0ull; hi[j] = 0ull;
            if (pass[j]) lo[j] = bits[w[j]];
        }
        #pragma unroll
        for (int j = 0; j < 8; ++j) {           // masked hi gathers (~0.6% lanes), CACHED
            if (pass[j] && s[j] > 57u)
                hi[j] = bits[(w[j] + 1u) & WORD_MASK];
        }
        vint4 r0, r1;
        #pragma unroll
        for (int j = 0; j < 8; ++j) {
            unsigned long long win = (lo[j] >> s[j]) | ((hi[j] << 1) << (63u - s[j]));
            int r = ((win & 0x7Full) == 0x7Full) ? 1 : 0;
            if (j < 4) r0[j] = r; else r1[j - 4] = r;
        }
        __builtin_nontemporal_store(r0, (vint4*)(out + base));
        __builtin_nontemporal_store(r1, (vint4*)(out + base + 4));
    } else {
        for (int j = base; j < n; ++j)
            out[j] = query_one_branchy((uint32_t)vals[j], bits);
    }
}

// ---------- fallback path (small ws): global-atomic insert + plain query ----------
__global__ __launch_bounds__(256) void zero_bits_kernel(vull2* __restrict__ bits, int n2) {
    int i = blockIdx.x * 256 + threadIdx.x;
    if (i < n2) { vull2 z = {0ull, 0ull}; __builtin_nontemporal_store(z, &bits[i]); }
}

__device__ __forceinline__ void insert_one_atomic(uint32_t v,
                                                  unsigned long long* __restrict__ bits) {
    uint32_t p = (v * PRIME) & BIT_MASK;
    uint32_t w = p >> 6, s = p & 63u;
    atomicOr(bits + w, 0x7Full << s);
    if (s > 57u) atomicOr(bits + ((w + 1u) & WORD_MASK), 0x7Full >> (64u - s));
}

__global__ __launch_bounds__(256) void insert_atomic_kernel(const int* __restrict__ vals, int n,
                                                            unsigned long long* __restrict__ bits) {
    int t = blockIdx.x * 256 + threadIdx.x;
    int base = t * 4;
    if (base + 3 < n) {
        vint4 v = __builtin_nontemporal_load((const vint4*)vals + t);
        insert_one_atomic((uint32_t)v.x, bits);
        insert_one_atomic((uint32_t)v.y, bits);
        insert_one_atomic((uint32_t)v.z, bits);
        insert_one_atomic((uint32_t)v.w, bits);
    } else {
        for (int j = base; j < n; ++j) insert_one_atomic((uint32_t)vals[j], bits);
    }
}

__global__ __launch_bounds__(256) void query_kernel8(
    const int* __restrict__ vals, int n,
    const unsigned long long* __restrict__ bits, int* __restrict__ out)
{
    int t = blockIdx.x * 256 + threadIdx.x;
    int base = t * 8;
    if (base + 7 < n) {
        vint4 v0 = __builtin_nontemporal_load((const vint4*)(vals + base));
        vint4 v1 = __builtin_nontemporal_load((const vint4*)(vals + base + 4));
        vint4 r0, r1;
        #pragma unroll
        for (int j = 0; j < 8; ++j) {
            uint32_t v = (uint32_t)(j < 4 ? v0[j] : v1[j - 4]);
            int r = query_one_branchy(v, bits);
            if (j < 4) r0[j] = r; else r1[j - 4] = r;
        }
        __builtin_nontemporal_store(r0, (vint4*)(out + base));
        __builtin_nontemporal_store(r1, (vint4*)(out + base + 4));
    } else {
        for (int j = base; j < n; ++j)
            out[j] = query_one_branchy((uint32_t)vals[j], bits);
    }
}

extern "C" void kernel_launch(void* const* d_in, const int* in_sizes, int n_in,
                              void* d_out, int out_size, void* d_ws, size_t ws_size,
                              hipStream_t stream) {
    const int* add_values   = (const int*)d_in[0];
    const int* query_values = (const int*)d_in[1];
    const int n_add   = in_sizes[0];   // 4,000,000
    const int n_query = in_sizes[1];   // 8,000,000
    int* out = (int*)d_out;

    uint8_t* ws = (uint8_t*)d_ws;
    unsigned long long* bits = (unsigned long long*)ws;
    uint32_t* lists = (uint32_t*)(ws + 16777216);
    uint32_t* gcnt  = (uint32_t*)(ws + 34570240);
    unsigned long long* H2 = (unsigned long long*)(ws + 16777216);  // aliases lists

    const int threads8 = (n_query + 7) / 8;

    if (ws_size >= WS_FULL) {
        const uint32_t nchunks = ((uint32_t)n_add + CHUNK - 1u) / CHUNK;
        init_gcnt_kernel<<<1, 512, 0, stream>>>(gcnt);
        scatter_kernel<<<nchunks, 512, 0, stream>>>(add_values, n_add, lists, gcnt);
        build_bitmap_kernel<<<NBUCKETS, 512, 0, stream>>>(lists, gcnt, bits);
        build_h2_kernel<<<H2_WORDS / 256, 256, 0, stream>>>(bits, H2);  // lists now dead
        query_kernelH2<<<(threads8 + 255) / 256, 256, 0, stream>>>(
            query_values, n_query, bits, H2, out);
    } else if (ws_size >= WS_H2_ONLY) {
        const int n2 = NUM_WORDS / 2;
        zero_bits_kernel<<<(n2 + 255) / 256, 256, 0, stream>>>((vull2*)bits, n2);
        const int threads4 = (n_add + 3) / 4;
        insert_atomic_kernel<<<(threads4 + 255) / 256, 256, 0, stream>>>(
            add_values, n_add, bits);
        build_h2_kernel<<<H2_WORDS / 256, 256, 0, stream>>>(bits, H2);
        query_kernelH2<<<(threads8 + 255) / 256, 256, 0, stream>>>(
            query_values, n_query, bits, H2, out);
    } else {
        const int n2 = NUM_WORDS / 2;
        zero_bits_kernel<<<(n2 + 255) / 256, 256, 0, stream>>>((vull2*)bits, n2);
        const int threads4 = (n_add + 3) / 4;
        insert_atomic_kernel<<<(threads4 + 255) / 256, 256, 0, stream>>>(
            add_values, n_add, bits);
        query_kernel8<<<(threads8 + 255) / 256, 256, 0, stream>>>(
            query_values, n_query, bits, out);
    }
}

// Round 7
// 179.536 us; speedup vs baseline: 1.1954x; 1.1954x over previous
//
#include <hip/hip_runtime.h>
#include <stdint.h>

// Bloom filter, 2^27 bits, 7 hashes = 7 CONSECUTIVE bits starting at
//   p = ((uint32)v * 2654435761u) & (2^27 - 1)   (wraps mod 2^27)
// Harness dtypes: integer inputs -> int32; bool output -> int32 (0/1).
//
// R15: consolidation — combine the empirically-best form of each phase.
//   R14 post-mortem: 8MB H2 table overflows the 4MiB per-XCD L2 -> 8M
//   random probes became post-L2 line fetches (FETCH 187->332MB, +18us).
//   Filter table must be <=4MB (L2-resident). Query reverted to R11's
//   proven 69us config (H nibble 4MB, 8/thread, cached gathers).
//   Insert = R12's best-measured bundle (~109us): CHUNK 8192 / 512-thread
//   scatter with wave-shuffle scan, full-region 512-thread build with
//   fused H. init_gcnt kernel replaced by hipMemsetAsync (saves a launch).

#define NUM_BITS_LOG2 27
#define NUM_BITS (1u << NUM_BITS_LOG2)
#define BIT_MASK (NUM_BITS - 1u)
#define NUM_WORDS (NUM_BITS >> 6)             // 2^21 u64 words = 16 MiB
#define WORD_MASK (NUM_WORDS - 1u)
#define PRIME 2654435761u
#define H_WORDS (NUM_WORDS >> 2)              // 2^19 u64 H-words = 4 MiB

#define NBUCKETS 512
#define BKT_SHIFT (NUM_BITS_LOG2 - 9)         // 18: region = 2^18 bits
#define REGION_WORDS (1u << (BKT_SHIFT - 6))  // 4096 u64 = 32 KiB
#define H_WORDS_PER_REGION (REGION_WORDS / 4) // 1024 u64 H-words per region
#define CAP 8688u                             // per-bucket list capacity (mean 7813 + 9.9 sigma)
#define CHUNK 8192u                           // values per sorted chunk (32 KiB LDS)

typedef int vint4 __attribute__((ext_vector_type(4)));
typedef unsigned long long vull2 __attribute__((ext_vector_type(2)));

// ---------------- workspace layout (bytes) ----------------
// [0, 16777216)            bits   u64 x 2^21   (16 MiB)
// [16777216, 20971520)     H      u64 x 2^19   (4 MiB)
// [20971520, 38764544)     lists  u32 x 512*8688
// [38764544, 38766592)     gcnt   u32 x 512
#define WS_H_ONLY 20971520ull
#define WS_FULL   38766592ull

// ---------- phase A: per-chunk LDS counting sort -> coalesced list flush ----------
// 512 threads/block, 1 bin/thread, wave-shuffle scan (3 syncs), 16 vals/thread.
__global__ __launch_bounds__(512) void scatter_kernel(
    const int* __restrict__ vals, int n,
    uint32_t* __restrict__ lists, uint32_t* __restrict__ gcnt)
{
    __shared__ uint32_t hist[NBUCKETS];
    __shared__ uint32_t cur[NBUCKETS];     // local slot cursors
    __shared__ uint32_t gdelta[NBUCKETS];  // slot i -> global list index (u32 wrap ok)
    __shared__ uint32_t wsum[8];
    __shared__ uint32_t wexc[8];
    __shared__ uint32_t total_s;
    __shared__ uint32_t sortbuf[CHUNK];
    const uint32_t tid = threadIdx.x;
    const uint32_t lane = tid & 63u;
    const uint32_t wv = tid >> 6;
    const uint32_t un = (uint32_t)n;
    const uint32_t nchunks = (un + CHUNK - 1u) / CHUNK;

    for (uint32_t c = blockIdx.x; c < nchunks; c += gridDim.x) {
        const uint32_t base = c * CHUNK;
        const bool full = (base + CHUNK <= un);

        hist[tid] = 0u;
        __syncthreads();

        // ---- pass 1: histogram (+ direct write of rare straddle dups) ----
        vint4 vv[4];                                    // 16 values/thread
        if (full) {
            const vint4* src = (const vint4*)(vals + base);
            #pragma unroll
            for (int k = 0; k < 4; ++k) vv[k] = src[(uint32_t)k * 512u + tid];
            #pragma unroll
            for (int k = 0; k < 4; ++k) {
                #pragma unroll
                for (int j = 0; j < 4; ++j) {
                    uint32_t p = ((uint32_t)vv[k][j] * PRIME) & BIT_MASK;
                    uint32_t b1 = p >> BKT_SHIFT;
                    atomicAdd(&hist[b1], 1u);
                    uint32_t b2 = ((p + 6u) & BIT_MASK) >> BKT_SHIFT;
                    if (b2 != b1) {                     // ~92 total in whole input
                        uint32_t s2 = atomicAdd(&gcnt[b2], 1u);
                        if (s2 < CAP) lists[b2 * CAP + s2] = p;
                    }
                }
            }
        } else {
            #pragma unroll
            for (int k = 0; k < 16; ++k) {
                uint32_t idx = base + (uint32_t)k * 512u + tid;
                if (idx < un) {
                    uint32_t p = ((uint32_t)vals[idx] * PRIME) & BIT_MASK;
                    uint32_t b1 = p >> BKT_SHIFT;
                    atomicAdd(&hist[b1], 1u);
                    uint32_t b2 = ((p + 6u) & BIT_MASK) >> BKT_SHIFT;
                    if (b2 != b1) {
                        uint32_t s2 = atomicAdd(&gcnt[b2], 1u);
                        if (s2 < CAP) lists[b2 * CAP + s2] = p;
                    }
                }
            }
        }
        __syncthreads();

        // ---- wave-shuffle inclusive scan over 512 bins ----
        const uint32_t c0 = hist[tid];
        uint32_t x = c0;
        #pragma unroll
        for (uint32_t d = 1; d < 64; d <<= 1) {
            uint32_t y = __shfl_up(x, d, 64);
            if (lane >= d) x += y;
        }
        if (lane == 63u) wsum[wv] = x;
        __syncthreads();
        if (wv == 0) {
            uint32_t t8 = (lane < 8u) ? wsum[lane] : 0u;
            #pragma unroll
            for (uint32_t d = 1; d < 8; d <<= 1) {
                uint32_t y = __shfl_up(t8, d, 64);
                if (lane >= d) t8 += y;
            }
            if (lane < 8u) wexc[lane] = t8 - wsum[lane];   // exclusive wave offset
        }
        __syncthreads();
        const uint32_t inc = x + wexc[wv];                 // inclusive scan of bin tid
        const uint32_t lb = inc - c0;                      // exclusive (local base)
        if (tid == NBUCKETS - 1) total_s = inc;

        // ---- reserve global chunk; slot->global mapping ----
        uint32_t go = c0 ? atomicAdd(&gcnt[tid], c0) : 0u;
        cur[tid] = lb;
        gdelta[tid] = tid * CAP + go - lb;                 // u32 wraparound exact
        __syncthreads();

        // ---- pass 2: counting-sort p values into LDS ----
        if (full) {
            #pragma unroll
            for (int k = 0; k < 4; ++k) {
                #pragma unroll
                for (int j = 0; j < 4; ++j) {
                    uint32_t p = ((uint32_t)vv[k][j] * PRIME) & BIT_MASK;
                    uint32_t b1 = p >> BKT_SHIFT;
                    uint32_t s = atomicAdd(&cur[b1], 1u);
                    sortbuf[s] = p;
                }
            }
        } else {
            #pragma unroll
            for (int k = 0; k < 16; ++k) {
                uint32_t idx = base + (uint32_t)k * 512u + tid;
                if (idx < un) {
                    uint32_t p = ((uint32_t)vals[idx] * PRIME) & BIT_MASK;
                    uint32_t b1 = p >> BKT_SHIFT;
                    uint32_t s = atomicAdd(&cur[b1], 1u);
                    sortbuf[s] = p;
                }
            }
        }
        __syncthreads();

        // ---- flush: slots grouped by ascending bucket -> coalesced run writes ----
        const uint32_t total = total_s;
        for (uint32_t i = tid; i < total; i += 512u) {
            uint32_t p = sortbuf[i];
            uint32_t b = p >> BKT_SHIFT;
            uint32_t dst = gdelta[b] + i;
            if (dst - b * CAP < CAP) lists[dst] = p;    // clamp: statistically unreachable
        }
        __syncthreads();                                // protect LDS reuse next iter
    }
}

// ---------- phase B: build region bitmap in LDS, emit bits + H ----------
__device__ __forceinline__ void set_window(unsigned long long* bm, uint32_t p, uint32_t b) {
    int d = (int)((p - (b << BKT_SHIFT)) & BIT_MASK);
    if (d >= (1 << 26)) d -= (1 << 27);                 // dup from prev region / wrap
    if (d < -6 || d >= (1 << BKT_SHIFT)) return;        // safety guard
    if (d < 0) {
        atomicOr(&bm[0], 0x7Full >> (uint32_t)(-d));
    } else {
        uint32_t w = (uint32_t)d >> 6, s = (uint32_t)d & 63u;
        atomicOr(&bm[w], 0x7Full << s);
        if (s > 57u) atomicOr(&bm[w + 1], 0x7Full >> (64u - s));  // slack word absorbs
    }
}

// 16 nibble-AND bits of one u64 fine word, compacted to low 16 bits
__device__ __forceinline__ unsigned long long nib16(unsigned long long a) {
    unsigned long long t = a & (a >> 1);
    unsigned long long u = t & (t >> 2);                // bit 4k = AND of bits 4k..4k+3
    u &= 0x1111111111111111ull;
    u |= u >> 3;  u &= 0x0303030303030303ull;
    u |= u >> 6;  u &= 0x000F000F000F000Full;
    u |= u >> 12; u &= 0x000000FF000000FFull;
    u |= u >> 24; return u & 0xFFFFull;
}

__global__ __launch_bounds__(512) void build_bitmap_kernel(
    const uint32_t* __restrict__ lists, const uint32_t* __restrict__ gcnt,
    unsigned long long* __restrict__ bits, unsigned long long* __restrict__ H)
{
    __shared__ unsigned long long bm[REGION_WORDS + 1];
    const uint32_t b = blockIdx.x, tid = threadIdx.x;
    for (uint32_t i = tid; i < REGION_WORDS + 1; i += 512) bm[i] = 0ull;
    __syncthreads();

    // dense bucket list -> fully coalesced cooperative read
    const uint32_t m = min(gcnt[b], CAP);
    const uint32_t base = b * CAP;
    for (uint32_t i = tid; i < m; i += 512) set_window(bm, lists[base + i], b);
    __syncthreads();

    const uint32_t out_base = b * REGION_WORDS;
    for (uint32_t i = tid; i < REGION_WORDS / 2; i += 512) {
        vull2 w; w[0] = bm[i * 2]; w[1] = bm[i * 2 + 1];
        *((vull2*)(bits + out_base) + i) = w;           // temporal: warm L3 for query
    }
    const uint32_t h_base = b * H_WORDS_PER_REGION;
    for (uint32_t i = tid; i < H_WORDS_PER_REGION; i += 512) {
        unsigned long long hw = nib16(bm[i * 4])
                              | (nib16(bm[i * 4 + 1]) << 16)
                              | (nib16(bm[i * 4 + 2]) << 32)
                              | (nib16(bm[i * 4 + 3]) << 48);
        H[h_base + i] = hw;                 // temporal: H wants to live in L2
    }
}

// ---------- query: H pre-filter (L2-resident), fine bitmap only on pass ----------
__device__ __forceinline__ int query_one_branchy(uint32_t v,
                                                 const unsigned long long* __restrict__ bits) {
    uint32_t p = (v * PRIME) & BIT_MASK;
    uint32_t w = p >> 6, s = p & 63u;
    unsigned long long lo = bits[w];
    unsigned long long win;
    if (s <= 57u) win = lo >> s;
    else win = (lo >> s) | (bits[(w + 1u) & WORD_MASK] << (64u - s));
    return ((win & 0x7Full) == 0x7Full) ? 1 : 0;
}

// R11's proven config: 8 queries/thread, nibble filter (4MB, L2-resident),
// cached fine gathers, NT streaming I/O. Measured 69us / VGPR 40.
__global__ __launch_bounds__(256) void query_kernelH(
    const int* __restrict__ vals, int n,
    const unsigned long long* __restrict__ bits,
    const uint32_t* __restrict__ H32, int* __restrict__ out)
{
    int t = blockIdx.x * 256 + threadIdx.x;
    int base = t * 8;
    if (base + 7 < n) {
        vint4 v0 = __builtin_nontemporal_load((const vint4*)(vals + base));
        vint4 v1 = __builtin_nontemporal_load((const vint4*)(vals + base + 4));
        uint32_t p[8], pass[8];
        #pragma unroll
        for (int j = 0; j < 4; ++j) {
            p[j]     = ((uint32_t)v0[j] * PRIME) & BIT_MASK;
            p[j + 4] = ((uint32_t)v1[j] * PRIME) & BIT_MASK;
        }
        #pragma unroll
        for (int j = 0; j < 8; ++j) {           // 8 independent L2-hit H probes
            uint32_t m = ((p[j] + 3u) & BIT_MASK) >> 2;
            pass[j] = (H32[m >> 5] >> (m & 31u)) & 1u;
        }
        unsigned long long lo[8], hi[8];
        uint32_t w[8], s[8];
        #pragma unroll
        for (int j = 0; j < 8; ++j) {           // masked fine gathers (~13% lanes), CACHED
            w[j] = p[j] >> 6; s[j] = p[j] & 63u;
            lo[j] = 0ull; hi[j] = 0ull;
            if (pass[j]) lo[j] = bits[w[j]];
        }
        #pragma unroll
        for (int j = 0; j < 8; ++j) {           // masked hi gathers (~1.1% lanes), CACHED
            if (pass[j] && s[j] > 57u)
                hi[j] = bits[(w[j] + 1u) & WORD_MASK];
        }
        vint4 r0, r1;
        #pragma unroll
        for (int j = 0; j < 8; ++j) {
            unsigned long long win = (lo[j] >> s[j]) | ((hi[j] << 1) << (63u - s[j]));
            int r = ((win & 0x7Full) == 0x7Full) ? 1 : 0;
            if (j < 4) r0[j] = r; else r1[j - 4] = r;
        }
        __builtin_nontemporal_store(r0, (vint4*)(out + base));
        __builtin_nontemporal_store(r1, (vint4*)(out + base + 4));
    } else {
        for (int j = base; j < n; ++j)
            out[j] = query_one_branchy((uint32_t)vals[j], bits);
    }
}

// ---------- fallback path (small ws): global-atomic insert + plain query ----------
__global__ __launch_bounds__(256) void zero_bits_kernel(vull2* __restrict__ bits, int n2) {
    int i = blockIdx.x * 256 + threadIdx.x;
    if (i < n2) { vull2 z = {0ull, 0ull}; __builtin_nontemporal_store(z, &bits[i]); }
}

__device__ __forceinline__ void insert_one_atomic(uint32_t v,
                                                  unsigned long long* __restrict__ bits) {
    uint32_t p = (v * PRIME) & BIT_MASK;
    uint32_t w = p >> 6, s = p & 63u;
    atomicOr(bits + w, 0x7Full << s);
    if (s > 57u) atomicOr(bits + ((w + 1u) & WORD_MASK), 0x7Full >> (64u - s));
}

__global__ __launch_bounds__(256) void insert_atomic_kernel(const int* __restrict__ vals, int n,
                                                            unsigned long long* __restrict__ bits) {
    int t = blockIdx.x * 256 + threadIdx.x;
    int base = t * 4;
    if (base + 3 < n) {
        vint4 v = __builtin_nontemporal_load((const vint4*)vals + t);
        insert_one_atomic((uint32_t)v.x, bits);
        insert_one_atomic((uint32_t)v.y, bits);
        insert_one_atomic((uint32_t)v.z, bits);
        insert_one_atomic((uint32_t)v.w, bits);
    } else {
        for (int j = base; j < n; ++j) insert_one_atomic((uint32_t)vals[j], bits);
    }
}

__global__ __launch_bounds__(256) void build_h_kernel(
    const unsigned long long* __restrict__ bits, unsigned long long* __restrict__ H)
{
    uint32_t i = blockIdx.x * 256 + threadIdx.x;        // [0, 2^19), grid exact
    const vull2* b2 = (const vull2*)bits + (size_t)i * 2;
    vull2 a = b2[0];
    vull2 b = b2[1];
    unsigned long long hw = nib16(a[0])
                          | (nib16(a[1]) << 16)
                          | (nib16(b[0]) << 32)
                          | (nib16(b[1]) << 48);
    H[i] = hw;
}

__global__ __launch_bounds__(256) void query_kernel8(
    const int* __restrict__ vals, int n,
    const unsigned long long* __restrict__ bits, int* __restrict__ out)
{
    int t = blockIdx.x * 256 + threadIdx.x;
    int base = t * 8;
    if (base + 7 < n) {
        vint4 v0 = __builtin_nontemporal_load((const vint4*)(vals + base));
        vint4 v1 = __builtin_nontemporal_load((const vint4*)(vals + base + 4));
        vint4 r0, r1;
        #pragma unroll
        for (int j = 0; j < 8; ++j) {
            uint32_t v = (uint32_t)(j < 4 ? v0[j] : v1[j - 4]);
            int r = query_one_branchy(v, bits);
            if (j < 4) r0[j] = r; else r1[j - 4] = r;
        }
        __builtin_nontemporal_store(r0, (vint4*)(out + base));
        __builtin_nontemporal_store(r1, (vint4*)(out + base + 4));
    } else {
        for (int j = base; j < n; ++j)
            out[j] = query_one_branchy((uint32_t)vals[j], bits);
    }
}

extern "C" void kernel_launch(void* const* d_in, const int* in_sizes, int n_in,
                              void* d_out, int out_size, void* d_ws, size_t ws_size,
                              hipStream_t stream) {
    const int* add_values   = (const int*)d_in[0];
    const int* query_values = (const int*)d_in[1];
    const int n_add   = in_sizes[0];   // 4,000,000
    const int n_query = in_sizes[1];   // 8,000,000
    int* out = (int*)d_out;

    uint8_t* ws = (uint8_t*)d_ws;
    unsigned long long* bits = (unsigned long long*)ws;
    unsigned long long* H    = (unsigned long long*)(ws + 16777216);
    uint32_t* lists = (uint32_t*)(ws + 20971520);
    uint32_t* gcnt  = (uint32_t*)(ws + 38764544);

    const int threads8 = (n_query + 7) / 8;

    if (ws_size >= WS_FULL) {
        const uint32_t nchunks = ((uint32_t)n_add + CHUNK - 1u) / CHUNK;
        hipMemsetAsync(gcnt, 0, NBUCKETS * sizeof(uint32_t), stream);
        scatter_kernel<<<nchunks, 512, 0, stream>>>(add_values, n_add, lists, gcnt);
        build_bitmap_kernel<<<NBUCKETS, 512, 0, stream>>>(lists, gcnt, bits, H);
        query_kernelH<<<(threads8 + 255) / 256, 256, 0, stream>>>(
            query_values, n_query, bits, (const uint32_t*)H, out);
    } else if (ws_size >= WS_H_ONLY) {
        const int n2 = NUM_WORDS / 2;
        zero_bits_kernel<<<(n2 + 255) / 256, 256, 0, stream>>>((vull2*)bits, n2);
        const int threads4 = (n_add + 3) / 4;
        insert_atomic_kernel<<<(threads4 + 255) / 256, 256, 0, stream>>>(
            add_values, n_add, bits);
        build_h_kernel<<<H_WORDS / 256, 256, 0, stream>>>(bits, H);
        query_kernelH<<<(threads8 + 255) / 256, 256, 0, stream>>>(
            query_values, n_query, bits, (const uint32_t*)H, out);
    } else {
        const int n2 = NUM_WORDS / 2;
        zero_bits_kernel<<<(n2 + 255) / 256, 256, 0, stream>>>((vull2*)bits, n2);
        const int threads4 = (n_add + 3) / 4;
        insert_atomic_kernel<<<(threads4 + 255) / 256, 256, 0, stream>>>(
            add_values, n_add, bits);
        query_kernel8<<<(threads8 + 255) / 256, 256, 0, stream>>>(
            query_values, n_query, bits, out);
    }
}